// Round 4
// baseline (693.195 us; speedup 1.0000x reference)
//
#include <hip/hip_runtime.h>

// GCN scatter-add: out[v] = sum_{(u,v) in E} features[u]
// Bucketed counting-partition (128 nodes/bucket) + LDS-tile gather-accumulate.

#define N_NODES   100000
#define N_EDGES   1000000
#define D_FEAT    64
#define NPB       128                          // nodes per bucket
#define NPB_SHIFT 7
#define NB        ((N_NODES + NPB - 1) / NPB)  // 782 buckets

__global__ void zero_ints_kernel(int* __restrict__ p, int n) {
    int i = blockIdx.x * blockDim.x + threadIdx.x;
    if (i < n) p[i] = 0;
}

// Bucket histogram, LDS-aggregated. n4 = n_edges/4 (int4 reads).
__global__ void bucket_hist_kernel(const int* __restrict__ dst,
                                   int* __restrict__ gcounts, int n4) {
    __shared__ int cnt[NB];
    for (int i = threadIdx.x; i < NB; i += blockDim.x) cnt[i] = 0;
    __syncthreads();
    int stride = gridDim.x * blockDim.x;
    for (int i = blockIdx.x * blockDim.x + threadIdx.x; i < n4; i += stride) {
        int4 d = ((const int4*)dst)[i];
        atomicAdd(&cnt[d.x >> NPB_SHIFT], 1);
        atomicAdd(&cnt[d.y >> NPB_SHIFT], 1);
        atomicAdd(&cnt[d.z >> NPB_SHIFT], 1);
        atomicAdd(&cnt[d.w >> NPB_SHIFT], 1);
    }
    __syncthreads();
    for (int i = threadIdx.x; i < NB; i += blockDim.x)
        if (cnt[i]) atomicAdd(&gcounts[i], cnt[i]);
}

// Exclusive scan of NB (<=1024) bucket counts -> bases, cursor. bases[NB]=n_edges.
__global__ __launch_bounds__(1024) void bucket_scan_kernel(const int* __restrict__ gcounts,
                                                           int* __restrict__ bases,
                                                           int* __restrict__ cursor,
                                                           int n_edges) {
    __shared__ int lds[1024];
    int t = threadIdx.x;
    int v = (t < NB) ? gcounts[t] : 0;
    lds[t] = v;
    __syncthreads();
    for (int off = 1; off < 1024; off <<= 1) {
        int u = (t >= off) ? lds[t - off] : 0;
        __syncthreads();
        lds[t] += u;
        __syncthreads();
    }
    if (t < NB) { int b = lds[t] - v; bases[t] = b; cursor[t] = b; }
    if (t == 0) bases[NB] = n_edges;
}

// Partition edges into bucket-contiguous packed pairs: (src<<7)|(dst&127).
// Writes advance per-bucket sequential frontiers -> L2 write-coalescing.
__global__ void partition_kernel(const int* __restrict__ src, const int* __restrict__ dst,
                                 int* __restrict__ cursor, int* __restrict__ pairs, int n4) {
    int i = blockIdx.x * blockDim.x + threadIdx.x;
    if (i >= n4) return;
    int4 s = ((const int4*)src)[i];
    int4 d = ((const int4*)dst)[i];
    int b, pos;
    b = d.x >> NPB_SHIFT; pos = atomicAdd(&cursor[b], 1); pairs[pos] = (s.x << NPB_SHIFT) | (d.x & (NPB - 1));
    b = d.y >> NPB_SHIFT; pos = atomicAdd(&cursor[b], 1); pairs[pos] = (s.y << NPB_SHIFT) | (d.y & (NPB - 1));
    b = d.z >> NPB_SHIFT; pos = atomicAdd(&cursor[b], 1); pairs[pos] = (s.z << NPB_SHIFT) | (d.z & (NPB - 1));
    b = d.w >> NPB_SHIFT; pos = atomicAdd(&cursor[b], 1); pairs[pos] = (s.w << NPB_SHIFT) | (d.w & (NPB - 1));
}

// One block per bucket: accumulate 128x64 out-tile in LDS, coalesced write-out.
__global__ __launch_bounds__(256) void gather_acc_kernel(const float* __restrict__ feat,
                                                         const int* __restrict__ bases,
                                                         const int* __restrict__ pairs,
                                                         float* __restrict__ out,
                                                         int n_nodes) {
    __shared__ float acc[NPB * D_FEAT];  // 32 KB
    int b = blockIdx.x;
    int t = threadIdx.x;

    float4* a4 = (float4*)acc;
    for (int i = t; i < NPB * D_FEAT / 4; i += 256) a4[i] = float4{0.f, 0.f, 0.f, 0.f};
    __syncthreads();

    int lo = bases[b], hi = bases[b + 1];
    int lane = t & 63;
    int wave = t >> 6;
    for (int i = lo + wave; i < hi; i += 4) {
        int p   = pairs[i];           // wave-uniform address -> broadcast
        int row = p & (NPB - 1);
        int sn  = p >> NPB_SHIFT;
        float v = feat[(size_t)sn * D_FEAT + lane];  // 256B coalesced row read
        atomicAdd(&acc[row * D_FEAT + lane], v);     // LDS f32 atomic, 2-way banks
    }
    __syncthreads();

    int node0 = b * NPB;
    int rows  = min(NPB, n_nodes - node0);
    int tot4  = rows * (D_FEAT / 4);
    float4* o4 = (float4*)(out + (size_t)node0 * D_FEAT);
    for (int i = t; i < tot4; i += 256) o4[i] = a4[i];
}

extern "C" void kernel_launch(void* const* d_in, const int* in_sizes, int n_in,
                              void* d_out, int out_size, void* d_ws, size_t ws_size,
                              hipStream_t stream) {
    const float* feat = (const float*)d_in[0];
    const int*   src  = (const int*)d_in[1];
    const int*   dst  = (const int*)d_in[2];
    float*       out  = (float*)d_out;

    const int n_edges = in_sizes[1];
    const int n4 = n_edges / 4;  // 1M divisible by 4

    // Workspace: gcounts[NB] | bases[NB+1] | cursor[NB] | pairs[E]  (~4.01 MB)
    int* gcounts = (int*)d_ws;
    int* bases   = gcounts + NB;
    int* cursor  = bases + NB + 1;
    int* pairs   = cursor + NB;

    zero_ints_kernel<<<(NB + 255) / 256, 256, 0, stream>>>(gcounts, NB);
    bucket_hist_kernel<<<256, 256, 0, stream>>>(dst, gcounts, n4);
    bucket_scan_kernel<<<1, 1024, 0, stream>>>(gcounts, bases, cursor, n_edges);
    partition_kernel<<<(n4 + 255) / 256, 256, 0, stream>>>(src, dst, cursor, pairs, n4);
    gather_acc_kernel<<<NB, 256, 0, stream>>>(feat, bases, pairs, out, N_NODES);
}

// Round 5
// 484.591 us; speedup vs baseline: 1.4305x; 1.4305x over previous
//
#include <hip/hip_runtime.h>

// GCN scatter-add: out[v] = sum_{(u,v) in E} features[u]
// Bucketed partition (128 nodes/bucket, block-range reservation) +
// LDS-tile gather-accumulate (8 waves, 4-deep ILP, staged pairs).

#define N_NODES   100000
#define N_EDGES   1000000
#define D_FEAT    64
#define NPB       128                          // nodes per bucket
#define NPB_SHIFT 7
#define NB        782                          // ceil(100000/128)
#define PAD       32                           // 128B-padded counters
#define PT        512                          // threads for hist/partition
#define STAGE     2048                         // pairs staged per chunk

__global__ void zero_ints_kernel(int* __restrict__ p, int n) {
    int i = blockIdx.x * blockDim.x + threadIdx.x;
    if (i < n) p[i] = 0;
}

// Per-block LDS histogram, padded global flush. One int4 (4 edges) per thread.
__global__ __launch_bounds__(PT) void hist_kernel(const int* __restrict__ dst,
                                                  int* __restrict__ gcounts, int n4) {
    __shared__ int cnt[NB];
    for (int i = threadIdx.x; i < NB; i += PT) cnt[i] = 0;
    __syncthreads();
    int i = blockIdx.x * PT + threadIdx.x;
    if (i < n4) {
        int4 d = ((const int4*)dst)[i];
        atomicAdd(&cnt[d.x >> NPB_SHIFT], 1);
        atomicAdd(&cnt[d.y >> NPB_SHIFT], 1);
        atomicAdd(&cnt[d.z >> NPB_SHIFT], 1);
        atomicAdd(&cnt[d.w >> NPB_SHIFT], 1);
    }
    __syncthreads();
    for (int b = threadIdx.x; b < NB; b += PT)
        if (cnt[b]) atomicAdd(&gcounts[b * PAD], cnt[b]);
}

// Exclusive scan of NB bucket counts -> bases (compact) + gcursor (padded).
__global__ __launch_bounds__(1024) void scan_kernel(const int* __restrict__ gcounts,
                                                    int* __restrict__ bases,
                                                    int* __restrict__ gcursor, int n_edges) {
    __shared__ int lds[1024];
    int t = threadIdx.x;
    int v = (t < NB) ? gcounts[t * PAD] : 0;
    lds[t] = v;
    __syncthreads();
    for (int off = 1; off < 1024; off <<= 1) {
        int u = (t >= off) ? lds[t - off] : 0;
        __syncthreads();
        lds[t] += u;
        __syncthreads();
    }
    if (t < NB) { int b = lds[t] - v; bases[t] = b; gcursor[t * PAD] = b; }
    if (t == 0) bases[NB] = n_edges;
}

// Partition into bucket-contiguous packed pairs (src<<7 | dst&127).
// Block reserves a contiguous per-bucket range with ONE padded atomic, then
// places its edges inside the range via LDS counters.
__global__ __launch_bounds__(PT) void partition_kernel(const int* __restrict__ src,
                                                       const int* __restrict__ dst,
                                                       int* __restrict__ gcursor,
                                                       int* __restrict__ pairs, int n4) {
    __shared__ int cnt[NB];
    __shared__ int lbase[NB];
    for (int i = threadIdx.x; i < NB; i += PT) cnt[i] = 0;
    __syncthreads();
    int i = blockIdx.x * PT + threadIdx.x;
    int4 s = {0, 0, 0, 0}, d = {0, 0, 0, 0};
    bool valid = (i < n4);
    if (valid) {
        s = ((const int4*)src)[i];
        d = ((const int4*)dst)[i];
        atomicAdd(&cnt[d.x >> NPB_SHIFT], 1);
        atomicAdd(&cnt[d.y >> NPB_SHIFT], 1);
        atomicAdd(&cnt[d.z >> NPB_SHIFT], 1);
        atomicAdd(&cnt[d.w >> NPB_SHIFT], 1);
    }
    __syncthreads();
    for (int b = threadIdx.x; b < NB; b += PT) {
        int c = cnt[b];
        lbase[b] = c ? atomicAdd(&gcursor[b * PAD], c) : 0;
    }
    __syncthreads();
    for (int b = threadIdx.x; b < NB; b += PT) cnt[b] = 0;  // reuse as placement ctr
    __syncthreads();
    if (valid) {
        int b, p;
        b = d.x >> NPB_SHIFT; p = atomicAdd(&cnt[b], 1); pairs[lbase[b] + p] = (s.x << NPB_SHIFT) | (d.x & (NPB - 1));
        b = d.y >> NPB_SHIFT; p = atomicAdd(&cnt[b], 1); pairs[lbase[b] + p] = (s.y << NPB_SHIFT) | (d.y & (NPB - 1));
        b = d.z >> NPB_SHIFT; p = atomicAdd(&cnt[b], 1); pairs[lbase[b] + p] = (s.z << NPB_SHIFT) | (d.z & (NPB - 1));
        b = d.w >> NPB_SHIFT; p = atomicAdd(&cnt[b], 1); pairs[lbase[b] + p] = (s.w << NPB_SHIFT) | (d.w & (NPB - 1));
    }
}

// One block (8 waves) per bucket: stage pairs in LDS chunks, 4-deep ILP feat
// reads, LDS f32 atomic accumulate into 128x64 tile, coalesced write-out.
__global__ __launch_bounds__(512) void gather_acc_kernel(const float* __restrict__ feat,
                                                         const int* __restrict__ bases,
                                                         const int* __restrict__ pairs,
                                                         float* __restrict__ out,
                                                         int n_nodes) {
    __shared__ float acc[NPB * D_FEAT];  // 32 KB
    __shared__ int   pbuf[STAGE];        // 8 KB
    int b = blockIdx.x, t = threadIdx.x;

    float4* a4 = (float4*)acc;
    for (int i = t; i < NPB * D_FEAT / 4; i += 512) a4[i] = float4{0.f, 0.f, 0.f, 0.f};

    int lo = bases[b], hi = bases[b + 1];
    int lane = t & 63;
    int wave = t >> 6;  // 0..7

    for (int chunk = lo; chunk < hi; chunk += STAGE) {
        int csz = min(STAGE, hi - chunk);
        __syncthreads();  // acc-init on 1st iter / pbuf reuse on later iters
        for (int i = t; i < csz; i += 512) pbuf[i] = pairs[chunk + i];
        __syncthreads();

        // groups of 4 edges; group g handled by wave g&7
        for (int k = wave * 4; k + 3 < csz; k += 32) {
            int p0 = pbuf[k], p1 = pbuf[k + 1], p2 = pbuf[k + 2], p3 = pbuf[k + 3];
            float v0 = feat[(size_t)(p0 >> NPB_SHIFT) * D_FEAT + lane];
            float v1 = feat[(size_t)(p1 >> NPB_SHIFT) * D_FEAT + lane];
            float v2 = feat[(size_t)(p2 >> NPB_SHIFT) * D_FEAT + lane];
            float v3 = feat[(size_t)(p3 >> NPB_SHIFT) * D_FEAT + lane];
            atomicAdd(&acc[(p0 & (NPB - 1)) * D_FEAT + lane], v0);
            atomicAdd(&acc[(p1 & (NPB - 1)) * D_FEAT + lane], v1);
            atomicAdd(&acc[(p2 & (NPB - 1)) * D_FEAT + lane], v2);
            atomicAdd(&acc[(p3 & (NPB - 1)) * D_FEAT + lane], v3);
        }
        // tail group (csz not multiple of 4): one wave mops up
        int kt = csz & ~3;
        if (kt < csz && wave == ((csz >> 2) & 7)) {
            for (int k = kt; k < csz; ++k) {
                int p = pbuf[k];
                float v = feat[(size_t)(p >> NPB_SHIFT) * D_FEAT + lane];
                atomicAdd(&acc[(p & (NPB - 1)) * D_FEAT + lane], v);
            }
        }
    }
    __syncthreads();

    int node0 = b * NPB;
    int rows  = min(NPB, n_nodes - node0);
    int tot4  = rows * (D_FEAT / 4);
    float4* o4 = (float4*)(out + (size_t)node0 * D_FEAT);
    for (int i = t; i < tot4; i += 512) o4[i] = a4[i];
}

extern "C" void kernel_launch(void* const* d_in, const int* in_sizes, int n_in,
                              void* d_out, int out_size, void* d_ws, size_t ws_size,
                              hipStream_t stream) {
    const float* feat = (const float*)d_in[0];
    const int*   src  = (const int*)d_in[1];
    const int*   dst  = (const int*)d_in[2];
    float*       out  = (float*)d_out;

    const int n_edges = in_sizes[1];
    const int n4 = n_edges / 4;  // 1M divisible by 4

    // Workspace: gcounts[NB*PAD] | gcursor[NB*PAD] | bases[NB+1] | pairs[E]
    int* gcounts = (int*)d_ws;
    int* gcursor = gcounts + NB * PAD;
    int* bases   = gcursor + NB * PAD;
    int* pairs   = bases + NB + 1;

    int nzero = NB * PAD;
    zero_ints_kernel<<<(nzero + 255) / 256, 256, 0, stream>>>(gcounts, nzero);

    int pblocks = (n4 + PT - 1) / PT;  // 489
    hist_kernel<<<pblocks, PT, 0, stream>>>(dst, gcounts, n4);
    scan_kernel<<<1, 1024, 0, stream>>>(gcounts, bases, gcursor, n_edges);
    partition_kernel<<<pblocks, PT, 0, stream>>>(src, dst, gcursor, pairs, n4);
    gather_acc_kernel<<<NB, 512, 0, stream>>>(feat, bases, pairs, out, N_NODES);
}

// Round 6
// 76.363 us; speedup vs baseline: 9.0776x; 6.3459x over previous
//
#include <hip/hip_runtime.h>

// GCN scatter-add: out[v] = sum_{(u,v) in E} features[u]
// Bucket partition (128 nodes/bucket, 8192-edge blocks) + fused gather:
// LDS counting-sort per bucket, REGISTER accumulation, coalesced row stores.

#define N_NODES   100000
#define N_EDGES   1000000
#define D_FEAT    64
#define NPB       128                 // nodes per bucket
#define NPB_SHIFT 7
#define NB        782                 // ceil(100000/128)
#define PAD       32                  // 128B-padded global counters
#define EPB       8192                // edges per hist/partition block
#define MAXP      4096                // max pairs staged per gather chunk

__global__ void zero_ints_kernel(int* __restrict__ p, int n) {
    int i = blockIdx.x * blockDim.x + threadIdx.x;
    if (i < n) p[i] = 0;
}

// Bucket histogram: 8192 edges/block, LDS-aggregated, padded global flush.
__global__ __launch_bounds__(512) void hist_kernel(const int* __restrict__ dst,
                                                   int* __restrict__ gcounts, int n) {
    __shared__ int cnt[NB];
    for (int i = threadIdx.x; i < NB; i += 512) cnt[i] = 0;
    __syncthreads();
    int base = blockIdx.x * EPB + threadIdx.x * 4;
#pragma unroll
    for (int step = 0; step < 4; ++step) {
        int idx = base + step * 2048;
        if (idx < n) {  // n % 4 == 0, idx % 4 == 0
            int4 d = *reinterpret_cast<const int4*>(dst + idx);
            atomicAdd(&cnt[d.x >> NPB_SHIFT], 1);
            atomicAdd(&cnt[d.y >> NPB_SHIFT], 1);
            atomicAdd(&cnt[d.z >> NPB_SHIFT], 1);
            atomicAdd(&cnt[d.w >> NPB_SHIFT], 1);
        }
    }
    __syncthreads();
    for (int b = threadIdx.x; b < NB; b += 512)
        if (cnt[b]) atomicAdd(&gcounts[b * PAD], cnt[b]);
}

// Exclusive scan of NB bucket counts -> bases (compact) + gcursor (padded).
__global__ __launch_bounds__(1024) void scan_kernel(const int* __restrict__ gcounts,
                                                    int* __restrict__ bases,
                                                    int* __restrict__ gcursor, int n_edges) {
    __shared__ int lds[1024];
    int t = threadIdx.x;
    int v = (t < NB) ? gcounts[t * PAD] : 0;
    lds[t] = v;
    __syncthreads();
    for (int off = 1; off < 1024; off <<= 1) {
        int u = (t >= off) ? lds[t - off] : 0;
        __syncthreads();
        lds[t] += u;
        __syncthreads();
    }
    if (t < NB) { int b = lds[t] - v; bases[t] = b; gcursor[t * PAD] = b; }
    if (t == 0) bases[NB] = n_edges;
}

// Partition into bucket-contiguous packed pairs (src<<7 | dst&127).
// 8192 edges/block: block reserves one contiguous range per touched bucket
// (runs of ~10 ints -> low write-line amplification), places via LDS cursors.
__global__ __launch_bounds__(512) void partition_kernel(const int* __restrict__ src,
                                                        const int* __restrict__ dst,
                                                        int* __restrict__ gcursor,
                                                        int* __restrict__ pairs, int n) {
    __shared__ int cnt[NB];
    __shared__ int lbase[NB];
    for (int i = threadIdx.x; i < NB; i += 512) cnt[i] = 0;
    __syncthreads();

    int base = blockIdx.x * EPB + threadIdx.x * 4;
    int4 s[4], d[4];
    bool valid[4];
#pragma unroll
    for (int step = 0; step < 4; ++step) {
        int idx = base + step * 2048;
        valid[step] = (idx < n);
        if (valid[step]) {
            s[step] = *reinterpret_cast<const int4*>(src + idx);
            d[step] = *reinterpret_cast<const int4*>(dst + idx);
            atomicAdd(&cnt[d[step].x >> NPB_SHIFT], 1);
            atomicAdd(&cnt[d[step].y >> NPB_SHIFT], 1);
            atomicAdd(&cnt[d[step].z >> NPB_SHIFT], 1);
            atomicAdd(&cnt[d[step].w >> NPB_SHIFT], 1);
        }
    }
    __syncthreads();
    for (int b = threadIdx.x; b < NB; b += 512) {
        int c = cnt[b];
        lbase[b] = c ? atomicAdd(&gcursor[b * PAD], c) : 0;
    }
    __syncthreads();
    for (int b = threadIdx.x; b < NB; b += 512) cnt[b] = 0;  // reuse as placement ctr
    __syncthreads();
#pragma unroll
    for (int step = 0; step < 4; ++step) {
        if (valid[step]) {
            int b, p;
            b = d[step].x >> NPB_SHIFT; p = atomicAdd(&cnt[b], 1); pairs[lbase[b] + p] = (s[step].x << NPB_SHIFT) | (d[step].x & (NPB - 1));
            b = d[step].y >> NPB_SHIFT; p = atomicAdd(&cnt[b], 1); pairs[lbase[b] + p] = (s[step].y << NPB_SHIFT) | (d[step].y & (NPB - 1));
            b = d[step].z >> NPB_SHIFT; p = atomicAdd(&cnt[b], 1); pairs[lbase[b] + p] = (s[step].z << NPB_SHIFT) | (d[step].z & (NPB - 1));
            b = d[step].w >> NPB_SHIFT; p = atomicAdd(&cnt[b], 1); pairs[lbase[b] + p] = (s[step].w << NPB_SHIFT) | (d[step].w & (NPB - 1));
        }
    }
}

// Fused gather: one block (8 waves) per bucket. LDS counting-sort of pairs,
// then each wave register-accumulates 16 nodes, coalesced 256B store each.
// Chunked (store-then-atomicAdd) for buckets > MAXP — correct for any size.
__global__ __launch_bounds__(512) void gather_kernel(const float* __restrict__ feat,
                                                     const int* __restrict__ bases,
                                                     const int* __restrict__ pairs,
                                                     float* __restrict__ out,
                                                     int n_nodes) {
    __shared__ int pbuf[MAXP];
    __shared__ int sorted[MAXP];
    __shared__ int deg[NPB];
    __shared__ int sc[NPB];
    __shared__ int start[NPB + 1];
    __shared__ int cur[NPB];

    int b = blockIdx.x, t = threadIdx.x;
    int lane = t & 63, wave = t >> 6;
    int lo = bases[b], hi = bases[b + 1];
    int node0 = b * NPB;

    bool first = true;
    for (int c = lo; c < hi || first; c += MAXP) {
        int n = hi - c;
        if (n > MAXP) n = MAXP;
        if (n < 0) n = 0;

        if (t < NPB) deg[t] = 0;
        __syncthreads();
        for (int i = t; i < n; i += 512) {
            int p = pairs[c + i];
            pbuf[i] = p;
            atomicAdd(&deg[p & (NPB - 1)], 1);
        }
        __syncthreads();
        // inclusive scan of deg over 128 entries (threads 0..127)
        if (t < NPB) sc[t] = deg[t];
        __syncthreads();
        for (int off = 1; off < NPB; off <<= 1) {
            int u = (t < NPB && t >= off) ? sc[t - off] : 0;
            __syncthreads();
            if (t < NPB) sc[t] += u;
            __syncthreads();
        }
        if (t < NPB) { start[t + 1] = sc[t]; cur[t] = sc[t] - deg[t]; }
        if (t == 0) start[0] = 0;
        __syncthreads();
        // scatter to node-sorted order in LDS
        for (int i = t; i < n; i += 512) {
            int p = pbuf[i];
            int r = p & (NPB - 1);
            int pos = atomicAdd(&cur[r], 1);
            sorted[pos] = p >> NPB_SHIFT;
        }
        __syncthreads();

        // register-accumulate: wave w owns nodes w, w+8, ..., 120+w
        for (int r = wave; r < NPB; r += 8) {
            int s0 = start[r], e0 = start[r + 1];
            float acc = 0.f;
            int i = s0;
            for (; i + 3 < e0; i += 4) {
                int i0 = sorted[i], i1 = sorted[i + 1], i2 = sorted[i + 2], i3 = sorted[i + 3];
                float v0 = feat[(size_t)i0 * D_FEAT + lane];
                float v1 = feat[(size_t)i1 * D_FEAT + lane];
                float v2 = feat[(size_t)i2 * D_FEAT + lane];
                float v3 = feat[(size_t)i3 * D_FEAT + lane];
                acc += v0 + v1 + v2 + v3;
            }
            for (; i < e0; ++i) acc += feat[(size_t)sorted[i] * D_FEAT + lane];

            int node = node0 + r;
            if (node < n_nodes) {
                float* o = out + (size_t)node * D_FEAT + lane;
                if (first) *o = acc;       // first chunk initializes (deg-0 -> 0)
                else atomicAdd(o, acc);    // rare: bucket spans multiple chunks
            }
        }
        first = false;
        __syncthreads();  // before LDS reuse in next chunk
    }
}

extern "C" void kernel_launch(void* const* d_in, const int* in_sizes, int n_in,
                              void* d_out, int out_size, void* d_ws, size_t ws_size,
                              hipStream_t stream) {
    const float* feat = (const float*)d_in[0];
    const int*   src  = (const int*)d_in[1];
    const int*   dst  = (const int*)d_in[2];
    float*       out  = (float*)d_out;

    const int n_edges = in_sizes[1];

    // Workspace: gcounts[NB*PAD] | gcursor[NB*PAD] | bases[NB+1] | pairs[E]
    int* gcounts = (int*)d_ws;
    int* gcursor = gcounts + NB * PAD;
    int* bases   = gcursor + NB * PAD;
    int* pairs   = bases + NB + 1;

    int nzero = NB * PAD;
    zero_ints_kernel<<<(nzero + 255) / 256, 256, 0, stream>>>(gcounts, nzero);

    int pblocks = (n_edges + EPB - 1) / EPB;  // 123
    hist_kernel<<<pblocks, 512, 0, stream>>>(dst, gcounts, n_edges);
    scan_kernel<<<1, 1024, 0, stream>>>(gcounts, bases, gcursor, n_edges);
    partition_kernel<<<pblocks, 512, 0, stream>>>(src, dst, gcursor, pairs, n_edges);
    gather_kernel<<<NB, 512, 0, stream>>>(feat, bases, pairs, out, N_NODES);
}